// Round 3
// baseline (273.778 us; speedup 1.0000x reference)
//
#include <hip/hip_runtime.h>
#include <math.h>

// Problem constants
constexpr int Bb = 4, Ll = 2048, Ss = 2048, Hh = 16, Ee = 64;
constexpr float SCALE = 0.125f;           // 1/sqrt(64)
constexpr float EPSV  = 1e-8f;
constexpr float S2E   = 0.125f * 1.44269504089f; // SCALE * log2(e)
constexpr float INV_CNT = 1.0f / (4.0f * 16.0f * 2048.0f * 2048.0f);

typedef __attribute__((ext_vector_type(8))) short  short8;   // 8 x bf16 bits
typedef __attribute__((ext_vector_type(4))) float  floatx4;  // MFMA C/D frag

#define MFMA __builtin_amdgcn_mfma_f32_16x16x32_bf16

// async global(16B/lane) -> LDS (wave-uniform base + lane*16)
#define GLL(gp, lp)                                                        \
  __builtin_amdgcn_global_load_lds(                                        \
      (const __attribute__((address_space(1))) unsigned int*)(gp),         \
      (__attribute__((address_space(3))) unsigned int*)(lp), 16, 0, 0)

__device__ __forceinline__ short f2bf(float f) {
  unsigned u = __builtin_bit_cast(unsigned, f);
  u += 0x7fffu + ((u >> 16) & 1u);  // RNE
  return (short)(u >> 16);
}
__device__ __forceinline__ float sq4(float4 v) {
  return v.x * v.x + v.y * v.y + v.z * v.z + v.w * v.w;
}
__device__ __forceinline__ short8 pack8(float4 x, float4 y) {
  short8 r;
  r[0] = f2bf(x.x); r[1] = f2bf(x.y); r[2] = f2bf(x.z); r[3] = f2bf(x.w);
  r[4] = f2bf(y.x); r[5] = f2bf(y.y); r[6] = f2bf(y.z); r[7] = f2bf(y.w);
  return r;
}

// ---------------- Pre-pass: K->bf16 [b][h][s][e], V->bf16^T [b][h][e][s], kn2 ----------------
__global__ __launch_bounds__(256) void geom_pre_kernel(
    const float* __restrict__ Kg, const float* __restrict__ Vg,
    short* __restrict__ Kbf, short* __restrict__ Vtg,
    float* __restrict__ kn2g, float* __restrict__ sumg) {
  __shared__ short Vl[64][72];
  const int tid = threadIdx.x;
  const int bid = blockIdx.x;
  const int st = bid & 31, h = (bid >> 5) & 15, b = bid >> 9;
  const int s0 = st * 64;
  const int r64 = tid >> 2, ec = (tid & 3) * 16;
  const int bh = b * 16 + h;

  if (bid == 0 && tid == 0) *sumg = 0.0f;  // zero scalar accumulator

  const float4* kp = (const float4*)(Kg + (((size_t)b * Ss + s0 + r64) * Hh + h) * Ee + ec);
  float4 k0 = kp[0], k1 = kp[1], k2 = kp[2], k3 = kp[3];
  float kn = sq4(k0) + sq4(k1) + sq4(k2) + sq4(k3);
  kn += __shfl_xor(kn, 1);
  kn += __shfl_xor(kn, 2);
  if ((tid & 3) == 0) kn2g[(size_t)bh * Ss + s0 + r64] = kn;
  short* ko = Kbf + ((size_t)bh * Ss + s0 + r64) * Ee + ec;
  *(short8*)(ko)     = pack8(k0, k1);
  *(short8*)(ko + 8) = pack8(k2, k3);

  const float4* vp = (const float4*)(Vg + (((size_t)b * Ss + s0 + r64) * Hh + h) * Ee + ec);
  float4 v0 = vp[0], v1 = vp[1], v2 = vp[2], v3 = vp[3];
  *(short8*)(&Vl[r64][ec])     = pack8(v0, v1);
  *(short8*)(&Vl[r64][ec + 8]) = pack8(v2, v3);
  __syncthreads();
  const int e = tid >> 2, sc = (tid & 3) * 16;
  short8 t0, t1;
#pragma unroll
  for (int j = 0; j < 8; ++j) {
    t0[j] = Vl[sc + j][e];
    t1[j] = Vl[sc + 8 + j][e];
  }
  short* vo = Vtg + ((size_t)bh * Ee + e) * Ss + s0 + sc;
  *(short8*)(vo)     = t0;
  *(short8*)(vo + 8) = t1;
}

// ---------------- Main: flash attention, S^T orientation ----------------
// LDS map (bytes): K [0,8192)  V^T [8192,16384)  P (4 waves x 16 x 144) [16384,25600)
//                  lw [25600,25856)  red [25856,25872)
constexpr int VOFF = 8192, POFF = 16384, LWOFF = 25600, RDOFF = 25856;

__global__ __launch_bounds__(256, 6) void geom_attn_kernel(
    const float* __restrict__ Qg, const short* __restrict__ Kbf,
    const short* __restrict__ Vtg, const float* __restrict__ kn2g,
    float* __restrict__ outg, float* __restrict__ sumg) {
  __shared__ __align__(16) char smem[25872];

  const int tid  = threadIdx.x;
  const int w    = tid >> 6;
  const int lane = tid & 63;
  const int c    = lane & 15;
  const int q4   = lane >> 4;

  const int bid = blockIdx.x;
  const int lt = bid & 31, h = (bid >> 5) & 15, b = bid >> 9;
  const int l0 = lt * 64 + w * 16;
  const int bh = b * 16 + h;

  // ---- Q frags (B-operand; lane's row l = c) + qn2 (lane-constant) ----
  const float4* qp = (const float4*)(Qg + (((size_t)b * Ll + (l0 + c)) * Hh + h) * Ee);
  float4 a0 = qp[2 * q4], a1 = qp[2 * q4 + 1];
  float4 a2 = qp[8 + 2 * q4], a3 = qp[9 + 2 * q4];
  float qn = sq4(a0) + sq4(a1) + sq4(a2) + sq4(a3);
  qn += __shfl_xor(qn, 16);
  qn += __shfl_xor(qn, 32);
  const float qn2v = qn;
  short8 qb0 = pack8(a0, a1);
  short8 qb1 = pack8(a2, a3);

  // ---- staging source/dest (XOR-swizzled granules) ----
  const int Gl = w * 128 + lane;            // instr0 granule; instr1 = +64
  const int rK = Gl >> 3, pK = Gl & 7;
  const int gK = pK ^ (rK & 7);
  const char* kSrc = (const char*)Kbf + (size_t)bh * Ss * 128 + rK * 128 + gK * 16;
  const char* vSrc = (const char*)Vtg + (size_t)bh * Ee * 4096 + rK * 4096 + gK * 16;
  char* kDst = smem + w * 2048;
  char* vDst = smem + VOFF + w * 2048;

  // kn2 read direct from global (L1/L2 broadcast; 16 lanes share each float4)
  const float4* knp = (const float4*)(kn2g + (size_t)bh * Ss) + q4;  // + s0/4 + ct*4

  // ---- fragment read addresses (swizzled) ----
  const int addrA0 = c * 128 + ((q4 ^ (c & 7)) << 4);  // K ka0 / V kc=0
  const int addrA1 = addrA0 ^ 64;                      // K ka1 / V kc=1
  const char* pKa0 = smem + addrA0;
  const char* pKa1 = smem + addrA1;
  char* pPw  = smem + POFF + w * 2304;
  char* pPwr = pPw + c * 144 + q4 * 8;             // + ct*32  (C-layout write)
  const char* pPrd = pPw + c * 144 + q4 * 16;      // + kc*64  (A-frag read: k=q4*8+j)
  float* lw = (float*)(smem + LWOFF + w * 64);
  float* red = (float*)(smem + RDOFF);

  floatx4 o0 = {0.f, 0.f, 0.f, 0.f}, o1 = o0, o2 = o0, o3 = o0;
  float lp = 0.0f, scsum = 0.0f;

  for (int s0 = 0; s0 < Ss; s0 += 64) {
    __syncthreads();  // prior tile's LDS reads done
    GLL(kSrc, kDst);
    GLL(kSrc + 1024, kDst + 1024);
    GLL(vSrc, vDst);
    GLL(vSrc + 32768, vDst + 1024);
    kSrc += 8192;  // 64 s-rows * 128 B
    vSrc += 128;   // 64 s-cols * 2 B
    __syncthreads();  // staging landed

    // ---- K·Q^T -> S^T tile; lane holds s = ct*16 + q4*4 + r, l = c ----
#pragma unroll
    for (int ct = 0; ct < 4; ++ct) {
      short8 ka0 = *(const short8*)(pKa0 + ct * 2048);
      short8 ka1 = *(const short8*)(pKa1 + ct * 2048);
      floatx4 d = {0.f, 0.f, 0.f, 0.f};
      d = MFMA(ka0, qb0, d, 0, 0, 0);
      d = MFMA(ka1, qb1, d, 0, 0, 0);
      float4 knv = knp[(s0 >> 2) + ct * 4];
      float p[4];
#pragma unroll
      for (int r = 0; r < 4; ++r) {
        float dot = d[r];
        float w2 = fmaf(-dot, dot, qn2v * (&knv.x)[r]);
        w2 = fmaxf(w2, EPSV);
        float rt = __builtin_amdgcn_sqrtf(w2);
        scsum += rt;                                  // * SCALE deferred to end
        float pe = __builtin_amdgcn_exp2f(rt * S2E);  // exp(score), no max-sub
        lp += pe;
        p[r] = pe;
      }
      // truncation bf16 pack (bias ~-0.2% on p cancels in o/l to ~0.002*|V|)
      uint2 pk;
      pk.x = __builtin_amdgcn_perm(__builtin_bit_cast(unsigned, p[1]),
                                   __builtin_bit_cast(unsigned, p[0]), 0x07060302u);
      pk.y = __builtin_amdgcn_perm(__builtin_bit_cast(unsigned, p[3]),
                                   __builtin_bit_cast(unsigned, p[2]), 0x07060302u);
      *(uint2*)(pPwr + ct * 32) = pk;   // wave-private: no barrier needed
    }

    // ---- P·V (P as A-operand from per-wave LDS, V^T as B-operand) ----
#pragma unroll
    for (int kc = 0; kc < 2; ++kc) {
      short8 pa = *(const short8*)(pPrd + kc * 64);
      const char* vb = (kc == 0 ? pKa0 : pKa1) + VOFF;
      short8 v0 = *(const short8*)(vb);
      short8 v1 = *(const short8*)(vb + 2048);
      short8 v2 = *(const short8*)(vb + 4096);
      short8 v3 = *(const short8*)(vb + 6144);
      o0 = MFMA(pa, v0, o0, 0, 0, 0);
      o1 = MFMA(pa, v1, o1, 0, 0, 0);
      o2 = MFMA(pa, v2, o2, 0, 0, 0);
      o3 = MFMA(pa, v3, o3, 0, 0, 0);
    }
  }

  // ---- finalize l (sum over the 4 q4 replicas), redistribute by row ----
  lp += __shfl_xor(lp, 16);
  lp += __shfl_xor(lp, 32);
  if (lane < 16) lw[lane] = lp;
  __syncthreads();
  float4 lv = *(const float4*)((const char*)lw + q4 * 16);

#pragma unroll
  for (int r = 0; r < 4; ++r) {
    float inv = 1.0f / (&lv.x)[r];
    int row = l0 + q4 * 4 + r;
    float* orow = outg + (((size_t)b * Ll + row) * Hh + h) * Ee;
    orow[0 + c]  = o0[r] * inv;
    orow[16 + c] = o1[r] * inv;
    orow[32 + c] = o2[r] * inv;
    orow[48 + c] = o3[r] * inv;
  }

  // ---- mean|scores| reduction ----
  scsum += __shfl_xor(scsum, 1);
  scsum += __shfl_xor(scsum, 2);
  scsum += __shfl_xor(scsum, 4);
  scsum += __shfl_xor(scsum, 8);
  scsum += __shfl_xor(scsum, 16);
  scsum += __shfl_xor(scsum, 32);
  if (lane == 0) red[w] = scsum;
  __syncthreads();
  if (tid == 0) {
    float s = red[0] + red[1] + red[2] + red[3];
    atomicAdd(sumg, s * (SCALE * INV_CNT));
  }
}

extern "C" void kernel_launch(void* const* d_in, const int* in_sizes, int n_in,
                              void* d_out, int out_size, void* d_ws, size_t ws_size,
                              hipStream_t stream) {
  const float* Q = (const float*)d_in[0];
  const float* K = (const float*)d_in[1];
  const float* V = (const float*)d_in[2];
  float* out   = (float*)d_out;
  float* sumsc = out + (size_t)Bb * Ll * Hh * Ee;

  // workspace: Kbf 16.78 MB | Vt 16.78 MB | kn2 0.52 MB  (requires ws >= 34.1 MB)
  short* Kbf = (short*)d_ws;
  short* Vtg = Kbf + (size_t)Bb * Hh * Ss * Ee;
  float* kn2 = (float*)(Vtg + (size_t)Bb * Hh * Ee * Ss);

  hipLaunchKernelGGL(geom_pre_kernel, dim3(Bb * Hh * (Ss / 64)), dim3(256), 0,
                     stream, K, V, Kbf, Vtg, kn2, sumsc);
  hipLaunchKernelGGL(geom_attn_kernel, dim3(Bb * Hh * (Ll / 64)), dim3(256), 0,
                     stream, Q, Kbf, Vtg, kn2, out, sumsc);
}

// Round 4
// 266.445 us; speedup vs baseline: 1.0275x; 1.0275x over previous
//
#include <hip/hip_runtime.h>
#include <math.h>

// Problem constants
constexpr int Bb = 4, Ll = 2048, Ss = 2048, Hh = 16, Ee = 64;
constexpr float S2E  = 0.125f * 1.44269504088896341f;  // SCALE * log2(e)
constexpr float EPS2 = 1e-8f * S2E * S2E;
constexpr float INV_CNT = 1.0f / (4.0f * 16.0f * 2048.0f * 2048.0f);
// scsum accumulates score*log2(e); convert back with ln2
constexpr float SUM_SCALE = INV_CNT * 0.69314718055994531f;

typedef __attribute__((ext_vector_type(8))) short  short8;   // 8 x bf16 bits
typedef __attribute__((ext_vector_type(4))) float  floatx4;  // MFMA C/D frag

#define MFMA __builtin_amdgcn_mfma_f32_16x16x32_bf16

// async global(16B/lane) -> LDS (wave-uniform dst base + lane*16)
#define GLL(gp, lp_)                                                       \
  __builtin_amdgcn_global_load_lds(                                        \
      (const __attribute__((address_space(1))) unsigned int*)(gp),         \
      (__attribute__((address_space(3))) unsigned int*)(lp_), 16, 0, 0)

__device__ __forceinline__ unsigned bfrnd(float f) {  // RNE, bf16 in high 16
  unsigned u = __builtin_bit_cast(unsigned, f);
  return u + 0x7fffu + ((u >> 16) & 1u);
}
__device__ __forceinline__ float sq4(float4 v) {
  return v.x * v.x + v.y * v.y + v.z * v.z + v.w * v.w;
}
__device__ __forceinline__ float4 mul4(float4 v, float s) {
  float4 r; r.x = v.x * s; r.y = v.y * s; r.z = v.z * s; r.w = v.w * s;
  return r;
}
__device__ __forceinline__ short8 pack8(float4 x, float4 y) {
  union { short8 s; unsigned u[4]; } r;
  r.u[0] = __builtin_amdgcn_perm(bfrnd(x.y), bfrnd(x.x), 0x07060302u);
  r.u[1] = __builtin_amdgcn_perm(bfrnd(x.w), bfrnd(x.z), 0x07060302u);
  r.u[2] = __builtin_amdgcn_perm(bfrnd(y.y), bfrnd(y.x), 0x07060302u);
  r.u[3] = __builtin_amdgcn_perm(bfrnd(y.w), bfrnd(y.z), 0x07060302u);
  return r.s;
}

// ---------- Pre-pass: K->bf16 [bh][s][e], V->bf16^T [bh][e][s], kn2 (LDS-free) ----------
__global__ __launch_bounds__(256) void geom_pre_kernel(
    const float* __restrict__ Kg, const float* __restrict__ Vg,
    short* __restrict__ Kbf, short* __restrict__ Vtg,
    float* __restrict__ kn2g, float* __restrict__ sumg) {
  const int tid = threadIdx.x, bid = blockIdx.x;
  const int st = bid & 31, h = (bid >> 5) & 15, b = bid >> 9;
  const int s0 = st * 64, bh = b * 16 + h;
  if (bid == 0 && tid == 0) *sumg = 0.0f;

  // K + kn2 (coalesced float4 reads, b128 bf16 writes)
  const int r64 = tid >> 2, ec = (tid & 3) * 16;
  const float4* kp = (const float4*)(Kg + (((size_t)b * Ss + s0 + r64) * Hh + h) * Ee + ec);
  float4 k0 = kp[0], k1 = kp[1], k2 = kp[2], k3 = kp[3];
  float kn = sq4(k0) + sq4(k1) + sq4(k2) + sq4(k3);
  kn += __shfl_xor(kn, 1);
  kn += __shfl_xor(kn, 2);
  if ((tid & 3) == 0) kn2g[(size_t)bh * Ss + s0 + r64] = kn;
  short* ko = Kbf + ((size_t)bh * Ss + s0 + r64) * Ee + ec;
  *(short8*)(ko)     = pack8(k0, k1);
  *(short8*)(ko + 8) = pack8(k2, k3);

  // V: 4x4 register-block transpose, no LDS
  const int sq = tid >> 4, eq = tid & 15;
  const float* vb = Vg + (((size_t)b * Ss + s0 + sq * 4) * Hh + h) * Ee + eq * 4;
  float4 r0 = *(const float4*)(vb);
  float4 r1 = *(const float4*)(vb + Hh * Ee);
  float4 r2 = *(const float4*)(vb + 2 * Hh * Ee);
  float4 r3 = *(const float4*)(vb + 3 * Hh * Ee);
  short* vo = Vtg + ((size_t)bh * Ee + eq * 4) * Ss + s0 + sq * 4;
#pragma unroll
  for (int j = 0; j < 4; ++j) {
    uint2 t;
    t.x = __builtin_amdgcn_perm(bfrnd((&r1.x)[j]), bfrnd((&r0.x)[j]), 0x07060302u);
    t.y = __builtin_amdgcn_perm(bfrnd((&r3.x)[j]), bfrnd((&r2.x)[j]), 0x07060302u);
    *(uint2*)(vo + (size_t)j * Ss) = t;
  }
}

// ---------- Main: flash attention, S^T orientation, BK=32, 2 l-groups/wave ----------
// LDS (bytes): K 2x4096 [0,8192)  V^T 2x4096 [8192,16384)
//              P 4 waves x 2 groups x 1024 [16384,24576)  kn2 [24576,32768)
constexpr int KB0 = 0, VB0 = 8192, PB = 16384, KN2 = 24576;

__global__ __launch_bounds__(256, 4) void geom_attn_kernel(
    const float* __restrict__ Qg, const short* __restrict__ Kbf,
    const short* __restrict__ Vtg, const float* __restrict__ kn2g,
    float* __restrict__ outg, float* __restrict__ sumg) {
  __shared__ __align__(16) char smem[32768];

  const int tid = threadIdx.x, w = tid >> 6, lane = tid & 63;
  const int c = lane & 15, q4 = lane >> 4;
  const int bid = blockIdx.x;
  const int lt = bid & 15, h = (bid >> 4) & 15, b = bid >> 8;
  const int bh = b * 16 + h;
  const int l0 = lt * 128 + w * 32;

  // Q fragments (B-operand), pre-scaled by S2E; qn2 in S2E^2 units (lane-const per group)
  short8 qb[2][2];
  float qn2v[2];
#pragma unroll
  for (int g = 0; g < 2; ++g) {
    const float4* qp = (const float4*)(Qg + (((size_t)b * Ll + l0 + g * 16 + c) * Hh + h) * Ee);
    float4 a0 = mul4(qp[2 * q4], S2E),     a1 = mul4(qp[2 * q4 + 1], S2E);
    float4 a2 = mul4(qp[8 + 2 * q4], S2E), a3 = mul4(qp[9 + 2 * q4], S2E);
    float qn = sq4(a0) + sq4(a1) + sq4(a2) + sq4(a3);
    qn += __shfl_xor(qn, 16);
    qn += __shfl_xor(qn, 32);
    qn2v[g] = qn;
    qb[g][0] = pack8(a0, a1);
    qb[g][1] = pack8(a2, a3);
  }

  // staging source pointers (XOR-swizzled 16B granules)
  const int rK = tid >> 3, pK = tid & 7;
  const char* kSrc = (const char*)Kbf + (size_t)bh * (Ss * 128) + rK * 128 + ((pK ^ (rK & 7)) * 16);
  const int eV = tid >> 2;
  const char* vSrc = (const char*)Vtg + (size_t)bh * (Ss * 128) + eV * (Ss * 2) + (((tid & 3) ^ (eV & 3)) * 16);
  char* kDstW = smem + KB0 + w * 1024;  // + buf*4096
  char* vDstW = smem + VB0 + w * 1024;

  // kn2 -> LDS once (8 KB; lgkm-domain reads thereafter)
  {
    const char* knSrc = (const char*)kn2g + (size_t)bh * 8192 + (size_t)tid * 16;
    GLL(knSrc, smem + KN2 + w * 1024);
    GLL(knSrc + 4096, smem + KN2 + w * 1024 + 4096);
  }

  // prologue: stage tile 0 into buffer 0
  GLL(kSrc, kDstW);
  GLL(vSrc, vDstW);
  kSrc += 4096;
  vSrc += 64;

  floatx4 o[2][4] = {};
  float lp0 = 0.f, lp1 = 0.f, scsum = 0.f;

  // fragment byte-offsets (swizzled)
  const int kOff = c * 128 + ((q4 ^ (c & 7)) * 16);  // + KB0 + buf*4096 + ct*2048 ; ka1 = ^64
  const int vOff = c * 64 + ((q4 ^ (c & 3)) * 16);   // + VB0 + buf*4096 + dt*1024
  const int pRd  = PB + w * 2048 + c * 64 + ((q4 ^ (c & 3)) * 16);  // + g*1024
  const int pWrB = PB + w * 2048 + c * 64 + (q4 & 1) * 8;           // + g*1024 + swz granule
  const int knRd = KN2 + q4 * 16;                    // + it*128 + ct*64

  for (int it = 0; it < 64; ++it) {
    const int p = it & 1;
    __syncthreads();  // tile it resident in buf p; prior compute done everywhere
    // prefetch tile it+1 (drained at NEXT barrier -> full tile of latency hiding)
    GLL(kSrc, kDstW + (p ^ 1) * 4096);
    GLL(vSrc, vDstW + (p ^ 1) * 4096);
    kSrc += 4096;
    vSrc += 64;

    const char* Kb = smem + KB0 + p * 4096;
    const char* Vb = smem + VB0 + p * 4096;

    // ---- K.Q^T -> S^T scores; lane holds s = ct*16+q4*4+r, l = c (per group) ----
#pragma unroll
    for (int ct = 0; ct < 2; ++ct) {
      short8 ka0 = *(const short8*)(Kb + ct * 2048 + kOff);
      short8 ka1 = *(const short8*)(Kb + ct * 2048 + (kOff ^ 64));
      float4 knv = *(const float4*)(smem + knRd + it * 128 + ct * 64);
      const int pwCT = ((ct * 2 + (q4 >> 1)) ^ (c & 3)) * 16;
#pragma unroll
      for (int g = 0; g < 2; ++g) {
        floatx4 d = {0.f, 0.f, 0.f, 0.f};
        d = MFMA(ka0, qb[g][0], d, 0, 0, 0);
        d = MFMA(ka1, qb[g][1], d, 0, 0, 0);
        float pe[4];
#pragma unroll
        for (int r = 0; r < 4; ++r) {
          float dot = d[r];
          float w2 = fmaf(-dot, dot, qn2v[g] * (&knv.x)[r]);
          w2 = fmaxf(w2, EPS2);
          float rt = __builtin_amdgcn_sqrtf(w2);   // = score*log2(e)
          scsum += rt;
          float e = __builtin_amdgcn_exp2f(rt);    // exp(score), no max-sub (scores>=0, bounded)
          if (g == 0) lp0 += e; else lp1 += e;
          pe[r] = e;
        }
        uint2 pk;  // truncation bf16 pack (bias cancels in o/l)
        pk.x = __builtin_amdgcn_perm(__builtin_bit_cast(unsigned, pe[1]),
                                     __builtin_bit_cast(unsigned, pe[0]), 0x07060302u);
        pk.y = __builtin_amdgcn_perm(__builtin_bit_cast(unsigned, pe[3]),
                                     __builtin_bit_cast(unsigned, pe[2]), 0x07060302u);
        *(uint2*)(smem + pWrB + g * 1024 + pwCT) = pk;  // wave-private slot
      }
    }

    // ---- P.V: V frags in regs, reused across both l-groups ----
    short8 vb0 = *(const short8*)(Vb + vOff);
    short8 vb1 = *(const short8*)(Vb + 1024 + vOff);
    short8 vb2 = *(const short8*)(Vb + 2048 + vOff);
    short8 vb3 = *(const short8*)(Vb + 3072 + vOff);
#pragma unroll
    for (int g = 0; g < 2; ++g) {
      short8 pa = *(const short8*)(smem + pRd + g * 1024);
      o[g][0] = MFMA(pa, vb0, o[g][0], 0, 0, 0);
      o[g][1] = MFMA(pa, vb1, o[g][1], 0, 0, 0);
      o[g][2] = MFMA(pa, vb2, o[g][2], 0, 0, 0);
      o[g][3] = MFMA(pa, vb3, o[g][3], 0, 0, 0);
    }
  }

  __syncthreads();  // drain trailing prefetch before epilogue / endpgm

  // l sums: fold the 4 q4 replicas; redistribute to D-layout rows via shuffle
  lp0 += __shfl_xor(lp0, 16); lp0 += __shfl_xor(lp0, 32);
  lp1 += __shfl_xor(lp1, 16); lp1 += __shfl_xor(lp1, 32);

#pragma unroll
  for (int g = 0; g < 2; ++g) {
    float lpg = (g == 0) ? lp0 : lp1;
#pragma unroll
    for (int r = 0; r < 4; ++r) {
      float inv = 1.0f / __shfl(lpg, q4 * 4 + r);  // lane c = q4*4+r holds row's sum
      float* orow = outg + (((size_t)b * Ll + l0 + g * 16 + q4 * 4 + r) * Hh + h) * Ee;
      orow[c]      = o[g][0][r] * inv;
      orow[16 + c] = o[g][1][r] * inv;
      orow[32 + c] = o[g][2][r] * inv;
      orow[48 + c] = o[g][3][r] * inv;
    }
  }

  // mean|scores|: wave-reduce, one atomic per wave
  scsum += __shfl_xor(scsum, 1);
  scsum += __shfl_xor(scsum, 2);
  scsum += __shfl_xor(scsum, 4);
  scsum += __shfl_xor(scsum, 8);
  scsum += __shfl_xor(scsum, 16);
  scsum += __shfl_xor(scsum, 32);
  if (lane == 0) atomicAdd(sumg, scsum * SUM_SCALE);
}

extern "C" void kernel_launch(void* const* d_in, const int* in_sizes, int n_in,
                              void* d_out, int out_size, void* d_ws, size_t ws_size,
                              hipStream_t stream) {
  const float* Q = (const float*)d_in[0];
  const float* K = (const float*)d_in[1];
  const float* V = (const float*)d_in[2];
  float* out   = (float*)d_out;
  float* sumsc = out + (size_t)Bb * Ll * Hh * Ee;

  // workspace: Kbf 16.78 MB | Vt 16.78 MB | kn2 0.52 MB (ws >= 34.1 MB)
  short* Kbf = (short*)d_ws;
  short* Vtg = Kbf + (size_t)Bb * Hh * Ss * Ee;
  float* kn2 = (float*)(Vtg + (size_t)Bb * Hh * Ee * Ss);

  hipLaunchKernelGGL(geom_pre_kernel, dim3(Bb * Hh * (Ss / 64)), dim3(256), 0,
                     stream, K, V, Kbf, Vtg, kn2, sumsc);
  hipLaunchKernelGGL(geom_attn_kernel, dim3(Bb * Hh * (Ll / 128)), dim3(256), 0,
                     stream, Q, Kbf, Vtg, kn2, out, sumsc);
}